// Round 10
// baseline (116.348 us; speedup 1.0000x reference)
//
#include <hip/hip_runtime.h>

#define WST 72   // f16 LDS row stride (144 B = 9*16: aligned, benign banks)
#define LOG2E 1.44269504f

typedef __attribute__((ext_vector_type(4))) float    f32x4;
typedef __attribute__((ext_vector_type(2))) float    f32x2;
typedef __attribute__((ext_vector_type(8))) _Float16 f16x8;
typedef __attribute__((ext_vector_type(2))) _Float16 f16x2;
typedef __attribute__((ext_vector_type(2))) __fp16   fp16x2_raw;

union U8 { f16x8 v; f16x2 h[4]; };

__device__ __forceinline__ float rcp_f(float x) { return __builtin_amdgcn_rcpf(x); }
__device__ __forceinline__ float exp2_f(float x) { return __builtin_amdgcn_exp2f(x); }
__device__ __forceinline__ float fast_sigmoid(float x) {
    return rcp_f(1.0f + __expf(-x));
}
__device__ __forceinline__ float tanh_exp(float x) {
    return 1.0f - 2.0f * rcp_f(__expf(2.0f * x) + 1.0f);
}
__device__ __forceinline__ f16x2 pkrtz(float a, float b) {
    fp16x2_raw r = __builtin_amdgcn_cvt_pkrtz(a, b);
    return __builtin_bit_cast(f16x2, r);
}

// ---- weight staging: global f32 -> LDS f16 transposed (Wt[c*WST+k] = W[k][c]) ----
__device__ __forceinline__ void wload8(const float* __restrict__ W, int tid, float v[8]) {
#pragma unroll
    for (int i = 0; i < 8; ++i) v[i] = W[tid + i * 512];
}
__device__ __forceinline__ void wstore8(_Float16* Wt, int tid, const float v[8], float scale) {
#pragma unroll
    for (int i = 0; i < 8; ++i) {
        int idx = tid + i * 512;
        Wt[(idx & 63) * WST + (idx >> 6)] = (_Float16)(v[i] * scale);
    }
}
__device__ __forceinline__ void wload16(const float* __restrict__ W, int t256, float v[16]) {
#pragma unroll
    for (int i = 0; i < 16; ++i) v[i] = W[t256 + i * 256];
}

// one 16x16(x64) strip of a 64x64x64 GEMM: wave covers rows [arow..), cols
// [colb, colb+16) and [colb+16, colb+32). acc pre-loaded with bias.
__device__ __forceinline__ void gemm2(const _Float16* Act, int arow, int qd,
                                      const _Float16* Wt, int colb,
                                      f32x4 acc[2]) {
    f16x8 a0 = *(const f16x8*)(Act + arow * WST + qd * 8);
    f16x8 a1 = *(const f16x8*)(Act + arow * WST + 32 + qd * 8);
#pragma unroll
    for (int cc = 0; cc < 2; ++cc) {
        const _Float16* wr = Wt + (colb + cc * 16) * WST + qd * 8;
        f16x8 b0 = *(const f16x8*)(wr);
        f16x8 b1 = *(const f16x8*)(wr + 32);
        acc[cc] = __builtin_amdgcn_mfma_f32_16x16x32_f16(a0, b0, acc[cc], 0, 0, 0);
        acc[cc] = __builtin_amdgcn_mfma_f32_16x16x32_f16(a1, b1, acc[cc], 0, 0, 0);
    }
}

// One binary-phase i-row: tanh/gate A-fragments from EQ/EQg + 8 MFMA + gated
// accumulate into BACC. Macro so multiple expansions per loop iteration stay
// in one scheduling region with independent chains (R9: x2 chains = -2.5us,
// confirming the R6 36%-issue-efficiency diagnosis; this build: x4 chains).
#define BINARY_II(II, BACC) do {                                              \
    const float* qm_ = EQb  + (II) * 64;                                      \
    const float* qg_ = EQgb + (II) * 64;                                      \
    U8 am_[2], ag_[2];                                                        \
    _Pragma("unroll")                                                         \
    for (int kk = 0; kk < 2; ++kk) {                                          \
        int cb_ = kk * 32 + qd * 8;                                           \
        f32x4 qa_ = *(const f32x4*)(qm_ + cb_);                               \
        f32x4 qb_ = *(const f32x4*)(qm_ + cb_ + 4);                           \
        f32x4 ha_ = *(const f32x4*)(qg_ + cb_);                               \
        f32x4 hb_ = *(const f32x4*)(qg_ + cb_ + 4);                           \
        _Pragma("unroll")                                                     \
        for (int t = 0; t < 2; ++t) {                                         \
            float a0_ = __builtin_fmaf(pm[kk*2][2*t],   qa_[2*t],   1.0f);    \
            float a1_ = __builtin_fmaf(pm[kk*2][2*t+1], qa_[2*t+1], 1.0f);    \
            float ri_ = rcp_f(a0_ * a1_);                                     \
            am_[kk].h[t]     = pkrtz(ri_ * a1_, ri_ * a0_);                   \
            float b0_ = __builtin_fmaf(pm[kk*2+1][2*t],   qb_[2*t],   1.0f);  \
            float b1_ = __builtin_fmaf(pm[kk*2+1][2*t+1], qb_[2*t+1], 1.0f);  \
            float rj_ = rcp_f(b0_ * b1_);                                     \
            am_[kk].h[2 + t] = pkrtz(rj_ * b1_, rj_ * b0_);                   \
            float c0_ = __builtin_fmaf(pg[kk*2][2*t],   ha_[2*t],   1.0f);    \
            float c1_ = __builtin_fmaf(pg[kk*2][2*t+1], ha_[2*t+1], 1.0f);    \
            float rk_ = rcp_f(c0_ * c1_);                                     \
            ag_[kk].h[t]     = pkrtz(rk_ * c1_, rk_ * c0_);                   \
            float d0_ = __builtin_fmaf(pg[kk*2+1][2*t],   hb_[2*t],   1.0f);  \
            float d1_ = __builtin_fmaf(pg[kk*2+1][2*t+1], hb_[2*t+1], 1.0f);  \
            float rl_ = rcp_f(d0_ * d1_);                                     \
            ag_[kk].h[2 + t] = pkrtz(rl_ * d1_, rl_ * d0_);                   \
        }                                                                     \
    }                                                                         \
    _Pragma("unroll")                                                         \
    for (int cc = 0; cc < 4; ++cc) {                                          \
        f32x4 d_ = {bim[cc], bim[cc], bim[cc], bim[cc]};                      \
        d_ = __builtin_amdgcn_mfma_f32_16x16x32_f16(am_[0].v, bwm[cc][0], d_, 0, 0, 0); \
        d_ = __builtin_amdgcn_mfma_f32_16x16x32_f16(am_[1].v, bwm[cc][1], d_, 0, 0, 0); \
        f32x4 e_ = {big[cc], big[cc], big[cc], big[cc]};                      \
        e_ = __builtin_amdgcn_mfma_f32_16x16x32_f16(ag_[0].v, bwg[cc][0], e_, 0, 0, 0); \
        e_ = __builtin_amdgcn_mfma_f32_16x16x32_f16(ag_[1].v, bwg[cc][1], e_, 0, 0, 0); \
        float v0_ = exp2_f(e_[0]), v1_ = exp2_f(e_[1]);                       \
        float u0_ = 1.0f + v0_, u1_ = 1.0f + v1_;                             \
        float r01_ = rcp_f(u0_ * u1_);                                        \
        BACC[cc][0] = __builtin_fmaf(d_[0] * u1_, r01_, BACC[cc][0]);         \
        BACC[cc][1] = __builtin_fmaf(d_[1] * u0_, r01_, BACC[cc][1]);         \
        float v2_ = exp2_f(e_[2]), v3_ = exp2_f(e_[3]);                       \
        float u2_ = 1.0f + v2_, u3_ = 1.0f + v3_;                             \
        float r23_ = rcp_f(u2_ * u3_);                                        \
        BACC[cc][2] = __builtin_fmaf(d_[2] * u3_, r23_, BACC[cc][2]);         \
        BACC[cc][3] = __builtin_fmaf(d_[3] * u2_, r23_, BACC[cc][3]);         \
    }                                                                         \
} while (0)

// ---------------------------------------------------------------------------
// fused_all: block = (n, j-half), 512 thr / 8 waves, 1 block/CU. R4 prep +
// binary loop unrolled ii x4 with four disjoint accumulators (in-wave ILP;
// VGPR budget ~226 < 256 at 2 waves/SIMD - checked before building, R7 lesson).
// ---------------------------------------------------------------------------
__global__ __launch_bounds__(512, 2) void fused_all_kernel(
    const float* __restrict__ x,
    const float* __restrict__ W_lin, const float* __restrict__ b_lin,
    const float* __restrict__ Wu1,  const float* __restrict__ bu1,
    const float* __restrict__ Wu2,  const float* __restrict__ bu2,
    const float* __restrict__ Wug1, const float* __restrict__ bug1,
    const float* __restrict__ Wug2, const float* __restrict__ bug2,
    const float* __restrict__ Wb1,  const float* __restrict__ bb1,
    const float* __restrict__ Wb2,  const float* __restrict__ bb2,
    const float* __restrict__ Wbg1, const float* __restrict__ bbg1,
    const float* __restrict__ Wbg2, const float* __restrict__ bbg2,
    float* __restrict__ out)
{
    __shared__ __align__(16) char smem[152576];
    _Float16* WLs = (_Float16*)(smem);             // W_lin(T) -> Tu(+0)/Tg(+2304 elems)
    _Float16* SX  = (_Float16*)(smem + 9216);      // x(f16) -> Wu2(T)
    _Float16* SH  = (_Float16*)(smem + 18432);     // h (64x72 f16)
    _Float16* W1  = (_Float16*)(smem + 27648);     // Wb1P -> -2*Wb2
    _Float16* W2  = (_Float16*)(smem + 36864);     // Wb1Q -> 2log2e*Wbg2
    _Float16* W3  = (_Float16*)(smem + 46080);     // Wbg1P
    _Float16* W4  = (_Float16*)(smem + 55296);     // Wbg1Q
    _Float16* W5  = (_Float16*)(smem + 64512);     // Wu1
    _Float16* W6  = (_Float16*)(smem + 73728);     // Wug1
    _Float16* W7  = (_Float16*)(smem + 82944);     // Wug2(T)
    float*    EPm  = (float*)(smem + 92160);       // 32x68 f32 (8704 B)
    float*    EPgm = (float*)(smem + 100864);      // 32x68 f32
    float*    EQb  = (float*)(smem + 109568);      // 64x64 f32 (16384 B)
    float*    EQgb = (float*)(smem + 125952);      // 64x64 f32
    float*    um32 = (float*)(smem + 142336);      // 32x64 f32 (8192 B)
    float*    csP  = (float*)(smem + 150528);      // [8][64] f32 partials
    float*    Red  = (float*)(smem);               // 32768 B alias WLs..W1 (binary-dead)

    int tid = threadIdx.x, w = tid >> 6, l = tid & 63;
    int qd = l >> 4, l16 = l & 15;
    int n = blockIdx.x >> 1, jsel = blockIdx.x & 1;

    // full 64x64 gemm mapping: 4 row-quarters x 2 col-halves
    int rw = w & 3, ch = w >> 2;
    int arow = rw * 16 + l16;
    int colb = ch * 32 + l16;
    int crow = rw * 16 + qd * 4;

    // 32x64 strip mapping (P2 own-strip / P3): s = w&3
    int s = w & 3;
    int lr16 = (s & 1) * 16;
    int cb32 = (s >> 1) * 32;
    bool loW = (w < 4);                  // wave-uniform

    f32x4 acc[2];

    // ---- P0: stage x -> SX (f16), W_lin -> WLs ----
#pragma unroll
    for (int i = 0; i < 4; ++i) {
        int e = tid * 2 + i * 1024;
        f32x2 v = *(const f32x2*)(x + (size_t)n * 4096 + e);
        f16x2 p; p[0] = (_Float16)v[0]; p[1] = (_Float16)v[1];
        *(f16x2*)(SX + (e >> 6) * WST + (e & 63)) = p;
    }
    {
        float wv[8];
        wload8(W_lin, tid, wv);
        wstore8(WLs, tid, wv, 1.0f);
    }
    __syncthreads();

    // ---- P1: h = x@W_lin + b_lin -> SH; stage all 6 first-layer halves ----
    {
        float wv0[8], wv1[8], wv2[8], wv3[8], wv4[8], wv5[8];
        wload8(Wb1, tid, wv0);
        wload8(Wb1 + 4096, tid, wv1);
        wload8(Wbg1, tid, wv2);
        wload8(Wbg1 + 4096, tid, wv3);
        wload8(Wu1, tid, wv4);
        wload8(Wug1, tid, wv5);
#pragma unroll
        for (int cc = 0; cc < 2; ++cc) {
            float bv = b_lin[colb + cc * 16];
            acc[cc] = (f32x4){bv, bv, bv, bv};
        }
        gemm2(SX, arow, qd, WLs, colb, acc);
#pragma unroll
        for (int cc = 0; cc < 2; ++cc)
#pragma unroll
            for (int r = 0; r < 4; ++r)
                SH[(crow + r) * WST + colb + cc * 16] = (_Float16)acc[cc][r];
        wstore8(W1, tid, wv0, 1.0f);
        wstore8(W2, tid, wv1, 1.0f);
        wstore8(W3, tid, wv2, 1.0f);
        wstore8(W4, tid, wv3, 1.0f);
        wstore8(W5, tid, wv4, 1.0f);
        wstore8(W6, tid, wv5, 1.0f);
    }
    __syncthreads();

    // ---- P2 (mega): 4 independent gemm chains per wave, one barrier ----
    {
        float wu2v[8], wug2v[8];
        wload8(Wu2, tid, wu2v);
        wload8(Wug2, tid, wug2v);

        // EQ = exp(2*(h@Wb1Q)), no bias
        acc[0] = (f32x4){0.f, 0.f, 0.f, 0.f};
        acc[1] = (f32x4){0.f, 0.f, 0.f, 0.f};
        gemm2(SH, arow, qd, W2, colb, acc);
#pragma unroll
        for (int cc = 0; cc < 2; ++cc)
#pragma unroll
            for (int r = 0; r < 4; ++r)
                EQb[(crow + r) * 64 + colb + cc * 16] = __expf(2.0f * acc[cc][r]);

        // EQg = exp(2*(h@Wbg1Q)), no bias
        f32x4 accg[2];
        accg[0] = (f32x4){0.f, 0.f, 0.f, 0.f};
        accg[1] = (f32x4){0.f, 0.f, 0.f, 0.f};
        gemm2(SH, arow, qd, W4, colb, accg);
#pragma unroll
        for (int cc = 0; cc < 2; ++cc)
#pragma unroll
            for (int r = 0; r < 4; ++r)
                EQgb[(crow + r) * 64 + colb + cc * 16] = __expf(2.0f * accg[cc][r]);

        // own-strip work on rows jsel*32 + [lr16, lr16+16)
        const _Float16* Wp = loW ? W1 : W3;      // Wb1P : Wbg1P
        const _Float16* Wt = loW ? W5 : W6;      // Wu1  : Wug1
        const float* bp = loW ? bb1 : bbg1;
        const float* bt = loW ? bu1 : bug1;
        float* EPdst = loW ? EPm : EPgm;
        _Float16* Tdst = loW ? WLs : (WLs + 2304);  // Tu / Tg (32x72 each)

        f32x4 accp[2];
#pragma unroll
        for (int cc = 0; cc < 2; ++cc) {
            float bv = bp[cb32 + cc * 16 + l16];
            accp[cc] = (f32x4){bv, bv, bv, bv};
        }
        gemm2(SH, jsel * 32 + lr16 + l16, qd, Wp, cb32 + l16, accp);
#pragma unroll
        for (int cc = 0; cc < 2; ++cc)
#pragma unroll
            for (int r = 0; r < 4; ++r)
                EPdst[(lr16 + qd * 4 + r) * 68 + cb32 + cc * 16 + l16] =
                    __expf(2.0f * accp[cc][r]);

        f32x4 acct[2];
#pragma unroll
        for (int cc = 0; cc < 2; ++cc) {
            float bv = bt[cb32 + cc * 16 + l16];
            acct[cc] = (f32x4){bv, bv, bv, bv};
        }
        gemm2(SH, jsel * 32 + lr16 + l16, qd, Wt, cb32 + l16, acct);
#pragma unroll
        for (int cc = 0; cc < 2; ++cc)
#pragma unroll
            for (int r = 0; r < 4; ++r)
                Tdst[(lr16 + qd * 4 + r) * WST + cb32 + cc * 16 + l16] =
                    (_Float16)tanh_exp(acct[cc][r]);

        wstore8(SX, tid, wu2v, 1.0f);
        wstore8(W7, tid, wug2v, 1.0f);
    }
    __syncthreads();

    // ---- P3: waves 0-3: U/G/um; waves 4-7: binary-weight staging + csum ----
    if (loW) {
        f32x4 ua[2], ga[2];
#pragma unroll
        for (int cc = 0; cc < 2; ++cc) {
            float bv = bu2[cb32 + cc * 16 + l16];
            ua[cc] = (f32x4){bv, bv, bv, bv};
        }
        gemm2(WLs, lr16 + l16, qd, SX, cb32 + l16, ua);
#pragma unroll
        for (int cc = 0; cc < 2; ++cc) {
            float bv = bug2[cb32 + cc * 16 + l16];
            ga[cc] = (f32x4){bv, bv, bv, bv};
        }
        gemm2(WLs + 2304, lr16 + l16, qd, W7, cb32 + l16, ga);
#pragma unroll
        for (int cc = 0; cc < 2; ++cc)
#pragma unroll
            for (int r = 0; r < 4; ++r)
                um32[(lr16 + qd * 4 + r) * 64 + cb32 + cc * 16 + l16] =
                    ua[cc][r] * fast_sigmoid(ga[cc][r]);
    } else {
        int tid2 = tid - 256;                    // 0..255
        float wm[16], wg[16];
        wload16(Wb2, tid2, wm);
        wload16(Wbg2, tid2, wg);
        float csm = 0.0f, csg = 0.0f;
#pragma unroll
        for (int i = 0; i < 16; ++i) {
            int idx = tid2 + i * 256;
            int o = (idx & 63) * WST + (idx >> 6);
            _Float16 a = (_Float16)(wm[i] * -2.0f);
            _Float16 b = (_Float16)(wg[i] * (2.0f * LOG2E));
            W1[o] = a;
            W2[o] = b;
            csm += (float)a;
            csg += (float)b;
        }
        int q = tid2 >> 6, c = tid2 & 63;        // 4 partials per col per matrix
        csP[q * 64 + c] = csm;
        csP[256 + q * 64 + c] = csg;
    }
    __syncthreads();

    // =============== binary phase: ii+=4, quad accumulators (ILP x4) ===============
    int jgrp = w >> 2, iw = w & 3;

    // B fragments from staged weights
    f16x8 bwm[4][2], bwg[4][2];
#pragma unroll
    for (int cc = 0; cc < 4; ++cc)
#pragma unroll
        for (int kk = 0; kk < 2; ++kk) {
            bwm[cc][kk] = *(const f16x8*)(W1 + (cc * 16 + l16) * WST + kk * 32 + qd * 8);
            bwg[cc][kk] = *(const f16x8*)(W2 + (cc * 16 + l16) * WST + kk * 32 + qd * 8);
        }
    float bim[4], big[4];
#pragma unroll
    for (int cc = 0; cc < 4; ++cc) {
        int c = cc * 16 + l16;
        bim[cc] = bb2[c] -
            0.5f * (csP[c] + csP[64 + c] + csP[128 + c] + csP[192 + c]);
        big[cc] = -LOG2E * bbg2[c] -
            0.5f * (csP[256 + c] + csP[320 + c] + csP[384 + c] + csP[448 + c]);
    }

    // P fragments (loop-invariant, register-resident)
    const float* pr  = EPm  + (jgrp * 16 + l16) * 68;
    const float* pgr = EPgm + (jgrp * 16 + l16) * 68;
    f32x4 pm[4], pg[4];
    pm[0] = *(const f32x4*)(pr + qd * 8);
    pm[1] = *(const f32x4*)(pr + qd * 8 + 4);
    pm[2] = *(const f32x4*)(pr + 32 + qd * 8);
    pm[3] = *(const f32x4*)(pr + 32 + qd * 8 + 4);
    pg[0] = *(const f32x4*)(pgr + qd * 8);
    pg[1] = *(const f32x4*)(pgr + qd * 8 + 4);
    pg[2] = *(const f32x4*)(pgr + 32 + qd * 8);
    pg[3] = *(const f32x4*)(pgr + 32 + qd * 8 + 4);

    f32x4 bacc0[4], bacc1[4], bacc2[4], bacc3[4];
#pragma unroll
    for (int cc = 0; cc < 4; ++cc) {
        bacc0[cc] = (f32x4){0.f, 0.f, 0.f, 0.f};
        bacc1[cc] = (f32x4){0.f, 0.f, 0.f, 0.f};
        bacc2[cc] = (f32x4){0.f, 0.f, 0.f, 0.f};
        bacc3[cc] = (f32x4){0.f, 0.f, 0.f, 0.f};
    }

    for (int ii = iw * 16; ii < iw * 16 + 16; ii += 4) {
        BINARY_II(ii,     bacc0);
        BINARY_II(ii + 1, bacc1);
        BINARY_II(ii + 2, bacc2);
        BINARY_II(ii + 3, bacc3);
    }
#pragma unroll
    for (int cc = 0; cc < 4; ++cc)
        bacc0[cc] = (bacc0[cc] + bacc1[cc]) + (bacc2[cc] + bacc3[cc]);

    __syncthreads();   // all waves done with W1/W2 frags + EQ/EP reads
#pragma unroll
    for (int cc = 0; cc < 4; ++cc)
#pragma unroll
        for (int r = 0; r < 4; ++r)
            Red[(jgrp * 4 + iw) * 1024 + (qd * 4 + r) * 64 + cc * 16 + l16] = bacc0[cc][r];
    __syncthreads();

    // reduce 4 i-ranges, add unary, write out
    {
        int e = tid * 4;                 // 512 thr x 4 = 2048 = 32x64
        int lr = e >> 6, col = e & 63;
        int g = lr >> 4, rr = lr & 15;
        f32x4 sv = {0.f, 0.f, 0.f, 0.f};
#pragma unroll
        for (int p = 0; p < 4; ++p)
            sv += *(const f32x4*)(Red + (g * 4 + p) * 1024 + rr * 64 + col);
        f32x4 u = *(const f32x4*)(um32 + lr * 64 + col);
        f32x4 o;
#pragma unroll
        for (int t = 0; t < 4; ++t)
            o[t] = u[t] + sv[t] * (1.0f / 63.0f);
        *(f32x4*)(out + (size_t)n * 4096 + (size_t)(jsel * 32 + lr) * 64 + col) = o;
    }
}

extern "C" void kernel_launch(void* const* d_in, const int* in_sizes, int n_in,
                              void* d_out, int out_size, void* d_ws, size_t ws_size,
                              hipStream_t stream)
{
    (void)in_sizes; (void)n_in; (void)out_size; (void)d_ws; (void)ws_size;
    const float* x     = (const float*)d_in[0];
    const float* W_lin = (const float*)d_in[1];
    const float* b_lin = (const float*)d_in[2];
    const float* Wu1   = (const float*)d_in[3];
    const float* bu1   = (const float*)d_in[4];
    const float* Wu2   = (const float*)d_in[5];
    const float* bu2   = (const float*)d_in[6];
    const float* Wug1  = (const float*)d_in[7];
    const float* bug1  = (const float*)d_in[8];
    const float* Wug2  = (const float*)d_in[9];
    const float* bug2  = (const float*)d_in[10];
    const float* Wb1   = (const float*)d_in[11];
    const float* bb1   = (const float*)d_in[12];
    const float* Wb2   = (const float*)d_in[13];
    const float* bb2   = (const float*)d_in[14];
    const float* Wbg1  = (const float*)d_in[15];
    const float* bbg1  = (const float*)d_in[16];
    const float* Wbg2  = (const float*)d_in[17];
    const float* bbg2  = (const float*)d_in[18];

    hipLaunchKernelGGL(fused_all_kernel, dim3(256), dim3(512), 0, stream,
        x, W_lin, b_lin, Wu1, bu1, Wu2, bu2, Wug1, bug1, Wug2, bug2,
        Wb1, bb1, Wb2, bb2, Wbg1, bbg1, Wbg2, bbg2,
        (float*)d_out);
}